// Round 1
// 606.027 us; speedup vs baseline: 1.0713x; 1.0713x over previous
//
#include <hip/hip_runtime.h>
#include <cstdint>
#include <cstddef>

#define S_DIM 4096
#define B_DIM 32
#define H_DIM 512
#define M_DIM (S_DIM * B_DIM)

typedef unsigned short u16;
typedef unsigned int u32;
typedef float f32x4 __attribute__((ext_vector_type(4)));
typedef __bf16 bf16x8 __attribute__((ext_vector_type(8)));

__device__ __forceinline__ u16 f2bf(float v) {
    union { float f; u32 u; } a; a.f = v;
    u32 r = a.u + 0x7fffu + ((a.u >> 16) & 1u);   // RNE
    return (u16)(r >> 16);
}
__device__ __forceinline__ float bf2f(u16 b) {
    union { float f; u32 u; } a; a.u = ((u32)b) << 16; return a.f;
}
__device__ __forceinline__ void split_bf(float v, u16& h, u16& l) {
    h = f2bf(v);
    l = f2bf(v - bf2f(h));
}

// async global->LDS, 16B per lane, dest = wave-uniform base + lane*16
__device__ __forceinline__ void gl2lds16(const void* g, void* l) {
    __builtin_amdgcn_global_load_lds(
        (const __attribute__((address_space(1))) unsigned int*)g,
        (__attribute__((address_space(3))) unsigned int*)l,
        16, 0, 0);
}

// ---------------------------------------------------------------------------
// Kernel 1: split W (fp32 [H,H] row-major j,k) into bf16 hi/lo pair.
// ---------------------------------------------------------------------------
__global__ void prep_w(const float* __restrict__ W,
                       u16* __restrict__ Wh, u16* __restrict__ Wl) {
    int i = blockIdx.x * 256 + threadIdx.x;       // grid 1024 -> 262144 elems
    float w = W[i];
    u16 h, l;
    split_bf(w, h, l);
    Wh[i] = h; Wl[i] = l;
}

// ---------------------------------------------------------------------------
// RNE hi/lo split of 4 products, packed to two uint2 (bit-identical to
// split_bf applied elementwise).
// ---------------------------------------------------------------------------
__device__ __forceinline__ void split4_store(
    float4 e, float4 h, u16* dh, u16* dl)
{
    float vf[4] = { e.x * h.x, e.y * h.y, e.z * h.z, e.w * h.w };
    u32 rh[4], rl[4];
    #pragma unroll
    for (int i = 0; i < 4; ++i) {
        const u32 u = __float_as_uint(vf[i]);
        rh[i] = (u + 0x7fffu + ((u >> 16) & 1u)) & 0xffff0000u;   // RNE hi, masked
        const float lo_f = vf[i] - __uint_as_float(rh[i]);         // exact
        const u32 ul = __float_as_uint(lo_f);
        rl[i] = ul + 0x7fffu + ((ul >> 16) & 1u);                  // RNE lo in [31:16]
    }
    uint2 hw, lw;
    hw.x = rh[1] | (rh[0] >> 16);
    hw.y = rh[3] | (rh[2] >> 16);
    lw.x = (rl[1] & 0xffff0000u) | (rl[0] >> 16);
    lw.y = (rl[3] & 0xffff0000u) | (rl[2] >> 16);
    *(uint2*)dh = hw;
    *(uint2*)dl = lw;
}

// ---------------------------------------------------------------------------
// Kernel 2 (fused): double-buffered 128x128 tile GEMM.
//   v[m,k] = enc[m,k]*hid[m&31,k] produced IN-KERNEL (reg stage + RNE split),
//   C[m,j] = sum_k v[m,k]*W[j,k]  (bf16x3 MFMA, fp32 accum),
//   Lp[jt][b][s] = sum_{j in jtile} enc[m-32, j] * C[m,j].
// One __syncthreads per K-step; next tile's B gl2lds + enc reg loads issued
// before current tile's MFMAs so global latency hides under compute.
// ---------------------------------------------------------------------------
__global__ __launch_bounds__(256, 2) void bigram_gemm_fused(
    const float* __restrict__ enc,
    const float* __restrict__ hid,
    const u16* __restrict__ Wh, const u16* __restrict__ Wl,
    float* __restrict__ Lp)
{
    __shared__ u16 sAh[2][128 * 32];
    __shared__ u16 sAl[2][128 * 32];
    __shared__ u16 sBh[2][128 * 32];
    __shared__ u16 sBl[2][128 * 32];
    __shared__ float rowsum[2][128];

    const int tid  = threadIdx.x;
    const int wave = tid >> 6;
    const int lane = tid & 63;
    const int wr   = wave >> 1;                   // wave row (0..1)
    const int wc   = wave & 1;                    // wave col (0..1)
    // bijective XCD-chunked swizzle (nwg=4096, 8 XCDs): all 4 jt of an mt on
    // one XCD, contiguous mt chunk per XCD -> enc rows reused in one L2.
    const int logical = (blockIdx.x & 7) * 512 + (blockIdx.x >> 3);
    const int jt   = logical & 3;
    const int mt   = logical >> 2;
    const int m0   = mt * 128;
    const int j0   = jt * 128;
    const int g    = lane >> 4;                   // quad 0..3
    const int cl   = lane & 15;

    // ---- B staging geometry (gload_lds): two 1KB segments per wave/buffer.
    const int srow = wave * 32 + (lane >> 2);
    const int scol = (lane & 3) * 8;
    const size_t boff0 = (size_t)(j0 + srow) * H_DIM + scol;
    const size_t boff1 = boff0 + (size_t)16 * H_DIM;
    const u16* pBh0 = Wh + boff0; const u16* pBh1 = Wh + boff1;
    const u16* pBl0 = Wl + boff0; const u16* pBl1 = Wl + boff1;
    const int d0 = wave * 1024, d1 = d0 + 512;    // u16 offsets

    // ---- A production geometry: thread covers 4 rows (q*32+abrow), 4 k each.
    const int abrow = tid >> 3;                   // 0..31 == b index (m0%32==0)
    const int akq   = tid & 7;                    // float4 slot in 32-k window
    const float* pe0 = enc + (size_t)(m0 +  0 + abrow) * H_DIM + akq * 4;
    const float* pe1 = enc + (size_t)(m0 + 32 + abrow) * H_DIM + akq * 4;
    const float* pe2 = enc + (size_t)(m0 + 64 + abrow) * H_DIM + akq * 4;
    const float* pe3 = enc + (size_t)(m0 + 96 + abrow) * H_DIM + akq * 4;
    const float* ph  = hid + (size_t)abrow * H_DIM + akq * 4;
    const int awoff = abrow * 32 + akq * 4;       // u16 offset (q adds q*1024)

    f32x4 acc[4][4];
    #pragma unroll
    for (int mf = 0; mf < 4; ++mf)
        #pragma unroll
        for (int nf = 0; nf < 4; ++nf)
            acc[mf][nf] = (f32x4){0.f, 0.f, 0.f, 0.f};

    // ---- prologue: stage tile 0 into buffer 0
    {
        gl2lds16(pBh0, &sBh[0][d0]);
        gl2lds16(pBh1, &sBh[0][d1]);
        gl2lds16(pBl0, &sBl[0][d0]);
        gl2lds16(pBl1, &sBl[0][d1]);
        const float4 h0 = *(const float4*)ph;
        const float4 e0 = *(const float4*)pe0;
        const float4 e1 = *(const float4*)pe1;
        const float4 e2 = *(const float4*)pe2;
        const float4 e3 = *(const float4*)pe3;
        split4_store(e0, h0, &sAh[0][0 * 1024 + awoff], &sAl[0][0 * 1024 + awoff]);
        split4_store(e1, h0, &sAh[0][1 * 1024 + awoff], &sAl[0][1 * 1024 + awoff]);
        split4_store(e2, h0, &sAh[0][2 * 1024 + awoff], &sAl[0][2 * 1024 + awoff]);
        split4_store(e3, h0, &sAh[0][3 * 1024 + awoff], &sAl[0][3 * 1024 + awoff]);
    }
    __syncthreads();

    #pragma unroll 2
    for (int kt = 0; kt < 16; ++kt) {
        const int cur = kt & 1, nxt = cur ^ 1;
        const int ko = (kt + 1) * 32;             // shorts / floats (next tile)

        float4 e0n, e1n, e2n, e3n, hn;
        if (kt < 15) {
            // issue next-tile staging early: loads fly during MFMA phase.
            gl2lds16(pBh0 + ko, &sBh[nxt][d0]);
            gl2lds16(pBh1 + ko, &sBh[nxt][d1]);
            gl2lds16(pBl0 + ko, &sBl[nxt][d0]);
            gl2lds16(pBl1 + ko, &sBl[nxt][d1]);
            e0n = *(const float4*)(pe0 + ko);
            e1n = *(const float4*)(pe1 + ko);
            e2n = *(const float4*)(pe2 + ko);
            e3n = *(const float4*)(pe3 + ko);
            hn  = *(const float4*)(ph + ko);
        }

        // ---- current-tile fragments + MFMA
        bf16x8 ah[4], al[4], bh[4], bl[4];
        #pragma unroll
        for (int mf = 0; mf < 4; ++mf) {
            const int ar = wr * 64 + mf * 16 + cl;
            ah[mf] = *(const bf16x8*)(&sAh[cur][ar * 32 + g * 8]);
            al[mf] = *(const bf16x8*)(&sAl[cur][ar * 32 + g * 8]);
        }
        #pragma unroll
        for (int nf = 0; nf < 4; ++nf) {
            const int br = wc * 64 + nf * 16 + cl;
            bh[nf] = *(const bf16x8*)(&sBh[cur][br * 32 + g * 8]);
            bl[nf] = *(const bf16x8*)(&sBl[cur][br * 32 + g * 8]);
        }
        #pragma unroll
        for (int mf = 0; mf < 4; ++mf)
            #pragma unroll
            for (int nf = 0; nf < 4; ++nf) {
                acc[mf][nf] = __builtin_amdgcn_mfma_f32_16x16x32_bf16(ah[mf], bh[nf], acc[mf][nf], 0, 0, 0);
                acc[mf][nf] = __builtin_amdgcn_mfma_f32_16x16x32_bf16(ah[mf], bl[nf], acc[mf][nf], 0, 0, 0);
                acc[mf][nf] = __builtin_amdgcn_mfma_f32_16x16x32_bf16(al[mf], bh[nf], acc[mf][nf], 0, 0, 0);
            }

        // ---- produce next-tile A into the other buffer (after MFMAs so the
        // vmcnt wait on enc lands late).
        if (kt < 15) {
            split4_store(e0n, hn, &sAh[nxt][0 * 1024 + awoff], &sAl[nxt][0 * 1024 + awoff]);
            split4_store(e1n, hn, &sAh[nxt][1 * 1024 + awoff], &sAl[nxt][1 * 1024 + awoff]);
            split4_store(e2n, hn, &sAh[nxt][2 * 1024 + awoff], &sAl[nxt][2 * 1024 + awoff]);
            split4_store(e3n, hn, &sAh[nxt][3 * 1024 + awoff], &sAl[nxt][3 * 1024 + awoff]);
        }
        __syncthreads();
    }

    // ---- single epilogue: rowsum[row] = sum_col enc[row-32, col] * C ----
    #pragma unroll
    for (int mf = 0; mf < 4; ++mf) {
        float rs0 = 0.f, rs1 = 0.f, rs2 = 0.f, rs3 = 0.f;
        const int growb = m0 + wr * 64 + mf * 16 + g * 4;
        #pragma unroll
        for (int nf = 0; nf < 4; ++nf) {
            const int gcol = j0 + wc * 64 + nf * 16 + cl;
            float e0 = (growb + 0 >= B_DIM) ? enc[(size_t)(growb + 0 - B_DIM) * H_DIM + gcol] : 0.f;
            float e1 = (growb + 1 >= B_DIM) ? enc[(size_t)(growb + 1 - B_DIM) * H_DIM + gcol] : 0.f;
            float e2 = (growb + 2 >= B_DIM) ? enc[(size_t)(growb + 2 - B_DIM) * H_DIM + gcol] : 0.f;
            float e3 = (growb + 3 >= B_DIM) ? enc[(size_t)(growb + 3 - B_DIM) * H_DIM + gcol] : 0.f;
            rs0 += acc[mf][nf][0] * e0;
            rs1 += acc[mf][nf][1] * e1;
            rs2 += acc[mf][nf][2] * e2;
            rs3 += acc[mf][nf][3] * e3;
        }
        #pragma unroll
        for (int off = 1; off < 16; off <<= 1) {
            rs0 += __shfl_xor(rs0, off);
            rs1 += __shfl_xor(rs1, off);
            rs2 += __shfl_xor(rs2, off);
            rs3 += __shfl_xor(rs3, off);
        }
        if (cl == 0) {
            const int rb = wr * 64 + mf * 16 + g * 4;   // disjoint across waves
            rowsum[wc][rb + 0] = rs0;
            rowsum[wc][rb + 1] = rs1;
            rowsum[wc][rb + 2] = rs2;
            rowsum[wc][rb + 3] = rs3;
        }
    }
    __syncthreads();
    if (tid < 128) {
        const int gm = m0 + tid;
        if (gm >= B_DIM) {
            Lp[(size_t)jt * M_DIM + (size_t)(gm & 31) * S_DIM + (gm >> 5)] =
                rowsum[0][tid] + rowsum[1][tid];
        }
    }
}

// ---------------------------------------------------------------------------
// Kernel 3a: per-b dots: Aux[b] = { h.aff0, h.aff1, h.aff2, h.enc[0,b] }
// ---------------------------------------------------------------------------
__global__ __launch_bounds__(256) void prep_aff(
    const float* __restrict__ enc,
    const float* __restrict__ hid,
    const float* __restrict__ aff,
    float* __restrict__ Aux)
{
    __shared__ float w[4][4];
    const int b    = blockIdx.x;
    const int tid  = threadIdx.x;
    const int wave = tid >> 6;
    const int lane = tid & 63;

    float p0 = 0.f, p1 = 0.f, p2 = 0.f, p3 = 0.f;
    #pragma unroll
    for (int it = 0; it < 2; ++it) {
        const int h = tid + it * 256;
        const float hv = hid[b * H_DIM + h];
        p0 += hv * aff[h * 3 + 0];
        p1 += hv * aff[h * 3 + 1];
        p2 += hv * aff[h * 3 + 2];
        p3 += hv * enc[(size_t)b * H_DIM + h];
    }
    #pragma unroll
    for (int off = 32; off > 0; off >>= 1) {
        p0 += __shfl_xor(p0, off);
        p1 += __shfl_xor(p1, off);
        p2 += __shfl_xor(p2, off);
        p3 += __shfl_xor(p3, off);
    }
    if (lane == 0) { w[wave][0] = p0; w[wave][1] = p1; w[wave][2] = p2; w[wave][3] = p3; }
    __syncthreads();
    if (tid < 4)
        Aux[b * 4 + tid] = w[0][tid] + w[1][tid] + w[2][tid] + w[3][tid];
}

// ---------------------------------------------------------------------------
// Kernel 3b: per-(b,strip) logits + partial (max, sum-of-exp).
// grid = 32*8 blocks of 256, each covers 512 s.
// ---------------------------------------------------------------------------
__global__ __launch_bounds__(256) void sm_partial(
    const float* __restrict__ emb,
    const float* __restrict__ Lp,
    const float* __restrict__ Aux,
    float* __restrict__ Lg,
    float* __restrict__ Part)
{
    __shared__ float wm[4];
    __shared__ float wsum[4];
    const int b     = blockIdx.x >> 3;
    const int strip = blockIdx.x & 7;
    const int tid   = threadIdx.x;
    const int wave  = tid >> 6;
    const int lane  = tid & 63;

    const float ha0 = Aux[b * 4 + 0], ha1 = Aux[b * 4 + 1],
                ha2 = Aux[b * 4 + 2], s0dot = Aux[b * 4 + 3];

    float lgv[2];
    float mx = -3.4e38f;
    #pragma unroll
    for (int it = 0; it < 2; ++it) {
        const int s = strip * 512 + it * 256 + tid;
        const size_t base = (size_t)b * S_DIM + s;
        const float ed = (s == 0) ? s0dot
            : (Lp[base] + Lp[(size_t)M_DIM + base] + Lp[2 * (size_t)M_DIM + base] + Lp[3 * (size_t)M_DIM + base]);
        const float* e = emb + (size_t)(s * B_DIM + b) * 3;
        const float lg = ed + ha0 * e[0] + ha1 * e[1] + ha2 * e[2];
        Lg[(size_t)b * S_DIM + s] = lg;
        lgv[it] = lg;
        mx = fmaxf(mx, lg);
    }
    #pragma unroll
    for (int off = 32; off > 0; off >>= 1) mx = fmaxf(mx, __shfl_xor(mx, off));
    if (lane == 0) wm[wave] = mx;
    __syncthreads();
    mx = fmaxf(fmaxf(wm[0], wm[1]), fmaxf(wm[2], wm[3]));

    float sum = __expf(lgv[0] - mx) + __expf(lgv[1] - mx);
    #pragma unroll
    for (int off = 32; off > 0; off >>= 1) sum += __shfl_xor(sum, off);
    if (lane == 0) wsum[wave] = sum;
    __syncthreads();
    if (tid == 0) {
        Part[(size_t)(b * 8 + strip) * 2 + 0] = mx;
        Part[(size_t)(b * 8 + strip) * 2 + 1] = wsum[0] + wsum[1] + wsum[2] + wsum[3];
    }
}

// ---------------------------------------------------------------------------
// Kernel 3c: combine partials, write normalized softmax.
// ---------------------------------------------------------------------------
__global__ __launch_bounds__(256) void sm_final(
    const float* __restrict__ Lg,
    const float* __restrict__ Part,
    float* __restrict__ out)
{
    const int b     = blockIdx.x >> 3;
    const int strip = blockIdx.x & 7;
    const int tid   = threadIdx.x;

    float M = -3.4e38f;
    #pragma unroll
    for (int i = 0; i < 8; ++i) M = fmaxf(M, Part[(size_t)(b * 8 + i) * 2]);
    float S = 0.f;
    #pragma unroll
    for (int i = 0; i < 8; ++i)
        S += Part[(size_t)(b * 8 + i) * 2 + 1] * __expf(Part[(size_t)(b * 8 + i) * 2] - M);
    const float inv = 1.0f / S;

    #pragma unroll
    for (int it = 0; it < 2; ++it) {
        const int s = strip * 512 + it * 256 + tid;
        out[(size_t)b * S_DIM + s] = __expf(Lg[(size_t)b * S_DIM + s] - M) * inv;
    }
}

// ---------------------------------------------------------------------------
extern "C" void kernel_launch(void* const* d_in, const int* in_sizes, int n_in,
                              void* d_out, int out_size, void* d_ws, size_t ws_size,
                              hipStream_t stream) {
    const float* hid = (const float*)d_in[0];   // [1,B,H]
    const float* enc = (const float*)d_in[1];   // [S,B,H]
    const float* emb = (const float*)d_in[2];   // [S,B,3]
    const float* Wm  = (const float*)d_in[3];   // [H,H]
    const float* aff = (const float*)d_in[4];   // [H,3]
    float* out = (float*)d_out;                 // [B,1,S]

    char* ws = (char*)d_ws;
    u16*   Wh  = (u16*)ws;                                       // 512 KB
    u16*   Wl  = (u16*)(ws + (512u << 10));                      // 512 KB
    float* Lp  = (float*)(ws + (1024u << 10));                   // 2 MB: Lp[4][B][S]
    float* Aux = (float*)(ws + (3072u << 10));                   // 512 B
    float* Lg  = (float*)(ws + (3072u << 10) + 1024);            // 512 KB
    float* Part= (float*)(ws + (3072u << 10) + 1024 + (512u << 10)); // 2 KB

    hipLaunchKernelGGL(prep_w, dim3(1024), dim3(256), 0, stream, Wm, Wh, Wl);
    hipLaunchKernelGGL(prep_aff, dim3(32), dim3(256), 0, stream, enc, hid, aff, Aux);
    hipLaunchKernelGGL(bigram_gemm_fused, dim3(4096), dim3(256), 0, stream,
                       enc, hid, Wh, Wl, Lp);
    hipLaunchKernelGGL(sm_partial, dim3(256), dim3(256), 0, stream,
                       emb, Lp, Aux, Lg, Part);
    hipLaunchKernelGGL(sm_final, dim3(256), dim3(256), 0, stream,
                       Lg, Part, out);
}

// Round 2
// 558.453 us; speedup vs baseline: 1.1626x; 1.0852x over previous
//
#include <hip/hip_runtime.h>
#include <cstdint>
#include <cstddef>

#define S_DIM 4096
#define B_DIM 32
#define H_DIM 512
#define M_DIM (S_DIM * B_DIM)

typedef unsigned short u16;
typedef unsigned int u32;
typedef float f32x4 __attribute__((ext_vector_type(4)));
typedef __bf16 bf16x8 __attribute__((ext_vector_type(8)));

__device__ __forceinline__ u16 f2bf(float v) {
    union { float f; u32 u; } a; a.f = v;
    u32 r = a.u + 0x7fffu + ((a.u >> 16) & 1u);   // RNE
    return (u16)(r >> 16);
}
__device__ __forceinline__ float bf2f(u16 b) {
    union { float f; u32 u; } a; a.u = ((u32)b) << 16; return a.f;
}
__device__ __forceinline__ void split_bf(float v, u16& h, u16& l) {
    h = f2bf(v);
    l = f2bf(v - bf2f(h));
}

// async global->LDS, 16B per lane, dest = wave-uniform base + lane*16
__device__ __forceinline__ void gl2lds16(const void* g, void* l) {
    __builtin_amdgcn_global_load_lds(
        (const __attribute__((address_space(1))) unsigned int*)g,
        (__attribute__((address_space(3))) unsigned int*)l,
        16, 0, 0);
}

// ---------------------------------------------------------------------------
// Kernel 1: split W (fp32 [H,H] row-major j,k) into bf16 hi/lo pair.
// ---------------------------------------------------------------------------
__global__ void prep_w(const float* __restrict__ W,
                       u16* __restrict__ Wh, u16* __restrict__ Wl) {
    int i = blockIdx.x * 256 + threadIdx.x;       // grid 1024 -> 262144 elems
    float w = W[i];
    u16 h, l;
    split_bf(w, h, l);
    Wh[i] = h; Wl[i] = l;
}

// ---------------------------------------------------------------------------
// RNE hi/lo split of 4 products, packed to two uint2 (bit-identical to
// split_bf applied elementwise).
// ---------------------------------------------------------------------------
__device__ __forceinline__ void split4_store(
    float4 e, float4 h, u16* dh, u16* dl)
{
    float vf[4] = { e.x * h.x, e.y * h.y, e.z * h.z, e.w * h.w };
    u32 rh[4], rl[4];
    #pragma unroll
    for (int i = 0; i < 4; ++i) {
        const u32 u = __float_as_uint(vf[i]);
        rh[i] = (u + 0x7fffu + ((u >> 16) & 1u)) & 0xffff0000u;   // RNE hi, masked
        const float lo_f = vf[i] - __uint_as_float(rh[i]);         // exact
        const u32 ul = __float_as_uint(lo_f);
        rl[i] = ul + 0x7fffu + ((ul >> 16) & 1u);                  // RNE lo in [31:16]
    }
    uint2 hw, lw;
    hw.x = rh[1] | (rh[0] >> 16);
    hw.y = rh[3] | (rh[2] >> 16);
    lw.x = (rl[1] & 0xffff0000u) | (rl[0] >> 16);
    lw.y = (rl[3] & 0xffff0000u) | (rl[2] >> 16);
    *(uint2*)dh = hw;
    *(uint2*)dl = lw;
}

// ---------------------------------------------------------------------------
// Kernel 2 (fused, v2a): 128x128 tile, A single-buffered (produced in-kernel),
// B double-buffered. 49KB LDS -> 3 blocks/CU. Two barriers per K-step:
//   [read A frags] b#1 [gl2lds B-next + split->A-next + enc prefetch + MFMA] b#2
// All global issue sits between b#1 and b#2 so the vmcnt(0) drain at b#2 has
// the split+MFMA phase in flight.
// ---------------------------------------------------------------------------
__global__ __launch_bounds__(256, 3) void bigram_gemm_fused(
    const float* __restrict__ enc,
    const float* __restrict__ hid,
    const u16* __restrict__ Wh, const u16* __restrict__ Wl,
    float* __restrict__ Lp)
{
    __shared__ u16 sAh[128 * 32];       // 8 KB  (single buffer)
    __shared__ u16 sAl[128 * 32];       // 8 KB
    __shared__ u16 sBh[2][128 * 32];    // 16 KB (double buffer)
    __shared__ u16 sBl[2][128 * 32];    // 16 KB
    __shared__ float rowsum[2][128];    // 1 KB

    const int tid  = threadIdx.x;
    const int wave = tid >> 6;
    const int lane = tid & 63;
    const int wr   = wave >> 1;                   // wave row (0..1)
    const int wc   = wave & 1;                    // wave col (0..1)
    // bijective XCD-chunked swizzle (nwg=4096, 8 XCDs)
    const int logical = (blockIdx.x & 7) * 512 + (blockIdx.x >> 3);
    const int jt   = logical & 3;
    const int mt   = logical >> 2;
    const int m0   = mt * 128;
    const int j0   = jt * 128;
    const int g    = lane >> 4;                   // quad 0..3
    const int cl   = lane & 15;

    // ---- B staging geometry (gload_lds): two 1KB segments per wave/buffer.
    const int srow = wave * 32 + (lane >> 2);
    const int scol = (lane & 3) * 8;
    const size_t boff0 = (size_t)(j0 + srow) * H_DIM + scol;
    const size_t boff1 = boff0 + (size_t)16 * H_DIM;
    const u16* pBh0 = Wh + boff0; const u16* pBh1 = Wh + boff1;
    const u16* pBl0 = Wl + boff0; const u16* pBl1 = Wl + boff1;
    const int d0 = wave * 1024, d1 = d0 + 512;    // u16 offsets

    // ---- A production geometry: thread covers 4 rows (q*32+abrow), 4 k each.
    const int abrow = tid >> 3;                   // 0..31 == b index (m0%32==0)
    const int akq   = tid & 7;                    // float4 slot in 32-k window
    const float* pe0 = enc + (size_t)(m0 +  0 + abrow) * H_DIM + akq * 4;
    const float* pe1 = enc + (size_t)(m0 + 32 + abrow) * H_DIM + akq * 4;
    const float* pe2 = enc + (size_t)(m0 + 64 + abrow) * H_DIM + akq * 4;
    const float* pe3 = enc + (size_t)(m0 + 96 + abrow) * H_DIM + akq * 4;
    const float* ph  = hid + (size_t)abrow * H_DIM + akq * 4;
    const int awoff = abrow * 32 + akq * 4;       // u16 offset (q adds q*1024)

    f32x4 acc[4][4];
    #pragma unroll
    for (int mf = 0; mf < 4; ++mf)
        #pragma unroll
        for (int nf = 0; nf < 4; ++nf)
            acc[mf][nf] = (f32x4){0.f, 0.f, 0.f, 0.f};

    // ---- prologue: A(0) via split, B[0] via gl2lds, prefetch enc(1).
    float4 e0 = *(const float4*)pe0;
    float4 e1 = *(const float4*)pe1;
    float4 e2 = *(const float4*)pe2;
    float4 e3 = *(const float4*)pe3;
    float4 eh = *(const float4*)ph;
    gl2lds16(pBh0, &sBh[0][d0]);
    gl2lds16(pBh1, &sBh[0][d1]);
    gl2lds16(pBl0, &sBl[0][d0]);
    gl2lds16(pBl1, &sBl[0][d1]);
    split4_store(e0, eh, sAh + 0 * 1024 + awoff, sAl + 0 * 1024 + awoff);
    split4_store(e1, eh, sAh + 1 * 1024 + awoff, sAl + 1 * 1024 + awoff);
    split4_store(e2, eh, sAh + 2 * 1024 + awoff, sAl + 2 * 1024 + awoff);
    split4_store(e3, eh, sAh + 3 * 1024 + awoff, sAl + 3 * 1024 + awoff);
    e0 = *(const float4*)(pe0 + 32);
    e1 = *(const float4*)(pe1 + 32);
    e2 = *(const float4*)(pe2 + 32);
    e3 = *(const float4*)(pe3 + 32);
    eh = *(const float4*)(ph + 32);
    __syncthreads();

#define GEMM_ITER(KT, CUR)                                                     \
  {                                                                            \
    bf16x8 ah[4], al[4];                                                       \
    _Pragma("unroll")                                                          \
    for (int mf = 0; mf < 4; ++mf) {                                           \
      const int ar = wr * 64 + mf * 16 + cl;                                   \
      ah[mf] = *(const bf16x8*)(sAh + ar * 32 + g * 8);                        \
      al[mf] = *(const bf16x8*)(sAl + ar * 32 + g * 8);                        \
    }                                                                          \
    __syncthreads(); /* b#1: all A-frag reads done; cheap (no vmem pending) */ \
    if ((KT) < 15) {                                                           \
      const int ko = ((KT) + 1) * 32;                                          \
      gl2lds16(pBh0 + ko, &sBh[(CUR) ^ 1][d0]);                                \
      gl2lds16(pBh1 + ko, &sBh[(CUR) ^ 1][d1]);                                \
      gl2lds16(pBl0 + ko, &sBl[(CUR) ^ 1][d0]);                                \
      gl2lds16(pBl1 + ko, &sBl[(CUR) ^ 1][d1]);                                \
      split4_store(e0, eh, sAh + 0 * 1024 + awoff, sAl + 0 * 1024 + awoff);    \
      split4_store(e1, eh, sAh + 1 * 1024 + awoff, sAl + 1 * 1024 + awoff);    \
      split4_store(e2, eh, sAh + 2 * 1024 + awoff, sAl + 2 * 1024 + awoff);    \
      split4_store(e3, eh, sAh + 3 * 1024 + awoff, sAl + 3 * 1024 + awoff);    \
    }                                                                          \
    if ((KT) < 14) {                                                           \
      const int ko2 = ((KT) + 2) * 32;                                         \
      e0 = *(const float4*)(pe0 + ko2);                                        \
      e1 = *(const float4*)(pe1 + ko2);                                        \
      e2 = *(const float4*)(pe2 + ko2);                                        \
      e3 = *(const float4*)(pe3 + ko2);                                        \
      eh = *(const float4*)(ph + ko2);                                         \
    }                                                                          \
    _Pragma("unroll")                                                          \
    for (int nf = 0; nf < 4; ++nf) {                                           \
      const int br = wc * 64 + nf * 16 + cl;                                   \
      const bf16x8 bh = *(const bf16x8*)(&sBh[(CUR)][br * 32 + g * 8]);        \
      const bf16x8 bl = *(const bf16x8*)(&sBl[(CUR)][br * 32 + g * 8]);        \
      _Pragma("unroll")                                                        \
      for (int mf = 0; mf < 4; ++mf) {                                         \
        acc[mf][nf] = __builtin_amdgcn_mfma_f32_16x16x32_bf16(ah[mf], bh, acc[mf][nf], 0, 0, 0); \
        acc[mf][nf] = __builtin_amdgcn_mfma_f32_16x16x32_bf16(ah[mf], bl, acc[mf][nf], 0, 0, 0); \
        acc[mf][nf] = __builtin_amdgcn_mfma_f32_16x16x32_bf16(al[mf], bh, acc[mf][nf], 0, 0, 0); \
      }                                                                        \
    }                                                                          \
    __syncthreads(); /* b#2: A writes + B[nxt] gl2lds + enc loads drained */   \
  }

    for (int kt = 0; kt < 16; kt += 2) {
        GEMM_ITER(kt, 0);
        GEMM_ITER(kt + 1, 1);
    }
#undef GEMM_ITER

    // ---- single epilogue: rowsum[row] = sum_col enc[row-32, col] * C ----
    #pragma unroll
    for (int mf = 0; mf < 4; ++mf) {
        float rs0 = 0.f, rs1 = 0.f, rs2 = 0.f, rs3 = 0.f;
        const int growb = m0 + wr * 64 + mf * 16 + g * 4;
        #pragma unroll
        for (int nf = 0; nf < 4; ++nf) {
            const int gcol = j0 + wc * 64 + nf * 16 + cl;
            float ee0 = (growb + 0 >= B_DIM) ? enc[(size_t)(growb + 0 - B_DIM) * H_DIM + gcol] : 0.f;
            float ee1 = (growb + 1 >= B_DIM) ? enc[(size_t)(growb + 1 - B_DIM) * H_DIM + gcol] : 0.f;
            float ee2 = (growb + 2 >= B_DIM) ? enc[(size_t)(growb + 2 - B_DIM) * H_DIM + gcol] : 0.f;
            float ee3 = (growb + 3 >= B_DIM) ? enc[(size_t)(growb + 3 - B_DIM) * H_DIM + gcol] : 0.f;
            rs0 += acc[mf][nf][0] * ee0;
            rs1 += acc[mf][nf][1] * ee1;
            rs2 += acc[mf][nf][2] * ee2;
            rs3 += acc[mf][nf][3] * ee3;
        }
        #pragma unroll
        for (int off = 1; off < 16; off <<= 1) {
            rs0 += __shfl_xor(rs0, off);
            rs1 += __shfl_xor(rs1, off);
            rs2 += __shfl_xor(rs2, off);
            rs3 += __shfl_xor(rs3, off);
        }
        if (cl == 0) {
            const int rb = wr * 64 + mf * 16 + g * 4;   // disjoint across waves
            rowsum[wc][rb + 0] = rs0;
            rowsum[wc][rb + 1] = rs1;
            rowsum[wc][rb + 2] = rs2;
            rowsum[wc][rb + 3] = rs3;
        }
    }
    __syncthreads();
    if (tid < 128) {
        const int gm = m0 + tid;
        if (gm >= B_DIM) {
            Lp[(size_t)jt * M_DIM + (size_t)(gm & 31) * S_DIM + (gm >> 5)] =
                rowsum[0][tid] + rowsum[1][tid];
        }
    }
}

// ---------------------------------------------------------------------------
// Kernel 3a: per-b dots: Aux[b] = { h.aff0, h.aff1, h.aff2, h.enc[0,b] }
// ---------------------------------------------------------------------------
__global__ __launch_bounds__(256) void prep_aff(
    const float* __restrict__ enc,
    const float* __restrict__ hid,
    const float* __restrict__ aff,
    float* __restrict__ Aux)
{
    __shared__ float w[4][4];
    const int b    = blockIdx.x;
    const int tid  = threadIdx.x;
    const int wave = tid >> 6;
    const int lane = tid & 63;

    float p0 = 0.f, p1 = 0.f, p2 = 0.f, p3 = 0.f;
    #pragma unroll
    for (int it = 0; it < 2; ++it) {
        const int h = tid + it * 256;
        const float hv = hid[b * H_DIM + h];
        p0 += hv * aff[h * 3 + 0];
        p1 += hv * aff[h * 3 + 1];
        p2 += hv * aff[h * 3 + 2];
        p3 += hv * enc[(size_t)b * H_DIM + h];
    }
    #pragma unroll
    for (int off = 32; off > 0; off >>= 1) {
        p0 += __shfl_xor(p0, off);
        p1 += __shfl_xor(p1, off);
        p2 += __shfl_xor(p2, off);
        p3 += __shfl_xor(p3, off);
    }
    if (lane == 0) { w[wave][0] = p0; w[wave][1] = p1; w[wave][2] = p2; w[wave][3] = p3; }
    __syncthreads();
    if (tid < 4)
        Aux[b * 4 + tid] = w[0][tid] + w[1][tid] + w[2][tid] + w[3][tid];
}

// ---------------------------------------------------------------------------
// Kernel 3b: per-(b,strip) logits + partial (max, sum-of-exp).
// grid = 32*8 blocks of 256, each covers 512 s.
// ---------------------------------------------------------------------------
__global__ __launch_bounds__(256) void sm_partial(
    const float* __restrict__ emb,
    const float* __restrict__ Lp,
    const float* __restrict__ Aux,
    float* __restrict__ Lg,
    float* __restrict__ Part)
{
    __shared__ float wm[4];
    __shared__ float wsum[4];
    const int b     = blockIdx.x >> 3;
    const int strip = blockIdx.x & 7;
    const int tid   = threadIdx.x;
    const int wave  = tid >> 6;
    const int lane  = tid & 63;

    const float ha0 = Aux[b * 4 + 0], ha1 = Aux[b * 4 + 1],
                ha2 = Aux[b * 4 + 2], s0dot = Aux[b * 4 + 3];

    float lgv[2];
    float mx = -3.4e38f;
    #pragma unroll
    for (int it = 0; it < 2; ++it) {
        const int s = strip * 512 + it * 256 + tid;
        const size_t base = (size_t)b * S_DIM + s;
        const float ed = (s == 0) ? s0dot
            : (Lp[base] + Lp[(size_t)M_DIM + base] + Lp[2 * (size_t)M_DIM + base] + Lp[3 * (size_t)M_DIM + base]);
        const float* e = emb + (size_t)(s * B_DIM + b) * 3;
        const float lg = ed + ha0 * e[0] + ha1 * e[1] + ha2 * e[2];
        Lg[(size_t)b * S_DIM + s] = lg;
        lgv[it] = lg;
        mx = fmaxf(mx, lg);
    }
    #pragma unroll
    for (int off = 32; off > 0; off >>= 1) mx = fmaxf(mx, __shfl_xor(mx, off));
    if (lane == 0) wm[wave] = mx;
    __syncthreads();
    mx = fmaxf(fmaxf(wm[0], wm[1]), fmaxf(wm[2], wm[3]));

    float sum = __expf(lgv[0] - mx) + __expf(lgv[1] - mx);
    #pragma unroll
    for (int off = 32; off > 0; off >>= 1) sum += __shfl_xor(sum, off);
    if (lane == 0) wsum[wave] = sum;
    __syncthreads();
    if (tid == 0) {
        Part[(size_t)(b * 8 + strip) * 2 + 0] = mx;
        Part[(size_t)(b * 8 + strip) * 2 + 1] = wsum[0] + wsum[1] + wsum[2] + wsum[3];
    }
}

// ---------------------------------------------------------------------------
// Kernel 3c: combine partials, write normalized softmax.
// ---------------------------------------------------------------------------
__global__ __launch_bounds__(256) void sm_final(
    const float* __restrict__ Lg,
    const float* __restrict__ Part,
    float* __restrict__ out)
{
    const int b     = blockIdx.x >> 3;
    const int strip = blockIdx.x & 7;
    const int tid   = threadIdx.x;

    float M = -3.4e38f;
    #pragma unroll
    for (int i = 0; i < 8; ++i) M = fmaxf(M, Part[(size_t)(b * 8 + i) * 2]);
    float S = 0.f;
    #pragma unroll
    for (int i = 0; i < 8; ++i)
        S += Part[(size_t)(b * 8 + i) * 2 + 1] * __expf(Part[(size_t)(b * 8 + i) * 2] - M);
    const float inv = 1.0f / S;

    #pragma unroll
    for (int it = 0; it < 2; ++it) {
        const int s = strip * 512 + it * 256 + tid;
        out[(size_t)b * S_DIM + s] = __expf(Lg[(size_t)b * S_DIM + s] - M) * inv;
    }
}

// ---------------------------------------------------------------------------
extern "C" void kernel_launch(void* const* d_in, const int* in_sizes, int n_in,
                              void* d_out, int out_size, void* d_ws, size_t ws_size,
                              hipStream_t stream) {
    const float* hid = (const float*)d_in[0];   // [1,B,H]
    const float* enc = (const float*)d_in[1];   // [S,B,H]
    const float* emb = (const float*)d_in[2];   // [S,B,3]
    const float* Wm  = (const float*)d_in[3];   // [H,H]
    const float* aff = (const float*)d_in[4];   // [H,3]
    float* out = (float*)d_out;                 // [B,1,S]

    char* ws = (char*)d_ws;
    u16*   Wh  = (u16*)ws;                                       // 512 KB
    u16*   Wl  = (u16*)(ws + (512u << 10));                      // 512 KB
    float* Lp  = (float*)(ws + (1024u << 10));                   // 2 MB: Lp[4][B][S]
    float* Aux = (float*)(ws + (3072u << 10));                   // 512 B
    float* Lg  = (float*)(ws + (3072u << 10) + 1024);            // 512 KB
    float* Part= (float*)(ws + (3072u << 10) + 1024 + (512u << 10)); // 2 KB

    hipLaunchKernelGGL(prep_w, dim3(1024), dim3(256), 0, stream, Wm, Wh, Wl);
    hipLaunchKernelGGL(prep_aff, dim3(32), dim3(256), 0, stream, enc, hid, aff, Aux);
    hipLaunchKernelGGL(bigram_gemm_fused, dim3(4096), dim3(256), 0, stream,
                       enc, hid, Wh, Wl, Lp);
    hipLaunchKernelGGL(sm_partial, dim3(256), dim3(256), 0, stream,
                       emb, Lp, Aux, Lg, Part);
    hipLaunchKernelGGL(sm_final, dim3(256), dim3(256), 0, stream,
                       Lg, Part, out);
}